// Round 7
// baseline (624.118 us; speedup 1.0000x reference)
//
#include <hip/hip_runtime.h>
#include <hip/hip_bf16.h>

// Problem constants (from reference)
#define NN 50000      // nodes
#define NE 800000     // edges
#define NS 2          // samples
#define DIN 128
#define DNOISE 64
#define DH0 192       // DIN + DNOISE
#define DOUT 256      // D0 == D1
#define NB 49         // scan blocks = ceil(NN/1024)

typedef __bf16 bf16x8 __attribute__((ext_vector_type(8)));
typedef float floatx4 __attribute__((ext_vector_type(4)));

// ---------------- bf16 helpers (uint = packed bf16 pair) ----------------

__device__ inline float bflo(unsigned int u) { return __uint_as_float(u << 16); }
__device__ inline float bfhi(unsigned int u) { return __uint_as_float(u & 0xffff0000u); }
__device__ inline unsigned short f2bf_bits(float x) {
    __hip_bfloat16 b = __float2bfloat16(x);
    return *reinterpret_cast<unsigned short*>(&b);
}
__device__ inline unsigned int pack2(float lo, float hi) {
    return (unsigned int)f2bf_bits(lo) | ((unsigned int)f2bf_bits(hi) << 16);
}

// ---------------- CSR build ----------------

__global__ void count_kernel(const int* __restrict__ dst, int* __restrict__ cnt) {
    int i = blockIdx.x * blockDim.x + threadIdx.x;
    if (i < NE) atomicAdd(&cnt[dst[i]], 1);
}

// Phase A: per-block reduce of counts -> bsum[49]
__global__ __launch_bounds__(1024) void scanA_kernel(const int* __restrict__ cnt, int* __restrict__ bsum) {
    int i = blockIdx.x * 1024 + threadIdx.x;
    int v = (i < NN) ? cnt[i] : 0;
    for (int off = 32; off > 0; off >>= 1) v += __shfl_down(v, off);
    __shared__ int wsum[16];
    if ((threadIdx.x & 63) == 0) wsum[threadIdx.x >> 6] = v;
    __syncthreads();
    if (threadIdx.x == 0) {
        int s = 0;
        for (int k = 0; k < 16; ++k) s += wsum[k];
        bsum[blockIdx.x] = s;
    }
}

// Phase B: exclusive scan of 49 block sums (single wave, shfl scan)
__global__ __launch_bounds__(64) void scanB_kernel(int* __restrict__ bsum) {
    int lane = threadIdx.x;
    int orig = (lane < NB) ? bsum[lane] : 0;
    int v = orig;
    for (int off = 1; off < 64; off <<= 1) {
        int t = __shfl_up(v, off);
        if (lane >= off) v += t;
    }
    if (lane < NB) bsum[lane] = v - orig;  // exclusive
}

// Phase C: intra-block scan + block offset -> row_ptr, cursor
__global__ __launch_bounds__(1024) void scanC_kernel(int* __restrict__ cnt, const int* __restrict__ bsum,
                                                     int* __restrict__ row_ptr) {
    __shared__ int buf[1024];
    int tid = threadIdx.x;
    int i = blockIdx.x * 1024 + tid;
    int v = (i < NN) ? cnt[i] : 0;
    buf[tid] = v;
    __syncthreads();
    for (int off = 1; off < 1024; off <<= 1) {
        int t = (tid >= off) ? buf[tid - off] : 0;
        __syncthreads();
        buf[tid] += t;
        __syncthreads();
    }
    int excl = buf[tid] - v + bsum[blockIdx.x];
    if (i < NN) { row_ptr[i + 1] = excl + v; cnt[i] = excl; }  // cnt becomes write cursor
    if (i == 0) row_ptr[0] = 0;
}

__global__ void fill_kernel(const int* __restrict__ src, const int* __restrict__ dst,
                            int* __restrict__ cursor, int* __restrict__ col_idx) {
    int i = blockIdx.x * blockDim.x + threadIdx.x;
    if (i < NE) {
        int p = atomicAdd(&cursor[dst[i]], 1);
        col_idx[p] = src[i];
    }
}

// ---------------- input prep: X fp32->bf16 + noise fp32 -> bitpacked uint2 ----------------
// blocks [0, XB4): X convert (float4 granularity). blocks [XB4, XB4+NR): noise rows.
// Noise branch ALSO writes the epsilon passthrough output (fuses old copy_eps).
#define XQ (NN * DIN / 4)          // 1.6M float4 units
#define XB4 ((XQ + 255) / 256)     // 6250
#define NR_BLOCKS ((NS * NN + 255) / 256)  // 391

__global__ void prep_kernel(const float* __restrict__ X, unsigned short* __restrict__ Xb,
                            const float* __restrict__ noise, uint2* __restrict__ Nbit,
                            float* __restrict__ out_eps) {
    int b = blockIdx.x;
    if (b < XB4) {
        int i = b * 256 + threadIdx.x;
        if (i < XQ) {
            float4 v = reinterpret_cast<const float4*>(X)[i];
            ushort4 o;
            o.x = f2bf_bits(v.x); o.y = f2bf_bits(v.y); o.z = f2bf_bits(v.z); o.w = f2bf_bits(v.w);
            reinterpret_cast<ushort4*>(Xb)[i] = o;
        }
    } else {
        int r = (b - XB4) * 256 + threadIdx.x;  // (s*NN + node)
        if (r < NS * NN) {
            const float4* p = reinterpret_cast<const float4*>(noise + (size_t)r * DNOISE);
            float4* oe = reinterpret_cast<float4*>(out_eps + (size_t)r * DNOISE);
            unsigned int lo = 0, hi = 0;
            for (int q = 0; q < 8; ++q) {
                float4 v = p[q];
                oe[q] = v;
                int base = q * 4;
                lo |= (v.x != 0.f ? 1u : 0u) << base;
                lo |= (v.y != 0.f ? 1u : 0u) << (base + 1);
                lo |= (v.z != 0.f ? 1u : 0u) << (base + 2);
                lo |= (v.w != 0.f ? 1u : 0u) << (base + 3);
            }
            for (int q = 8; q < 16; ++q) {
                float4 v = p[q];
                oe[q] = v;
                int base = q * 4 - 32;
                hi |= (v.x != 0.f ? 1u : 0u) << base;
                hi |= (v.y != 0.f ? 1u : 0u) << (base + 1);
                hi |= (v.z != 0.f ? 1u : 0u) << (base + 2);
                hi |= (v.w != 0.f ? 1u : 0u) << (base + 3);
            }
            uint2 o; o.x = lo; o.y = hi;
            Nbit[r] = o;
        }
    }
}

// ---------------- W pack: W[k][n] fp32 -> Wp[cg][j][n'] uint4 (bf16x8 along k) ----------------
// Wp element (16B) = bf16 of W[8j..8j+7][cg*64+n'], i.e. one MFMA B-fragment octet.

template <int K>
__global__ void pack_w(const float* __restrict__ W, uint4* __restrict__ Wp) {
    const int n = blockIdx.x;            // output col 0..255
    const int tj = threadIdx.x;          // k-octet 0..K/8-1
    if (tj < K / 8) {
        unsigned short h[8];
#pragma unroll
        for (int r = 0; r < 8; ++r)
            h[r] = f2bf_bits(W[(size_t)(tj * 8 + r) * DOUT + n]);
        uint4 o;
        o.x = (unsigned)h[0] | ((unsigned)h[1] << 16);
        o.y = (unsigned)h[2] | ((unsigned)h[3] << 16);
        o.z = (unsigned)h[4] | ((unsigned)h[5] << 16);
        o.w = (unsigned)h[6] | ((unsigned)h[7] << 16);
        Wp[(size_t)((n >> 6) * (K / 8) + tj) * 64 + (n & 63)] = o;
    }
}

// ---------------- FUSED layer 0: agg0 -> LDS z-tile -> GEMM x W0 -> h1 ----------------
// Block = 256 threads, 32 nodes (64 rows: s*32+nloc). Agg phase = 16 sub-steps of
// the proven agg0 inner loops (X x8 = two x4 brackets, summation order identical;
// noise bit-count untouched), writing the z0 row into a 24 KB LDS tile
// (row-major [64][96] uints, 16B XOR swizzle: uintidx ^= (row&7)<<2 to kill the
// 384B-stride bank conflict on ds_read_b128). One barrier. GEMM phase: wave w
// computes rows [w*16,w*16+16) x all 256 cols (acc[16] = 64 VGPR); A-frags from
// LDS, B-frags direct from L2-resident packed Wp (4 x 256B segments per wave
// instr); bias+relu+bf16 store expression identical to the verified gemm.
// Numerics identical to the split agg0+gemm0 pipeline (same f32 chains, same
// bf16 bits into the same MFMA sequence).

__global__ __launch_bounds__(256, 4) void fused0_kernel(
    const unsigned int* __restrict__ Xb,   // [NN][64] packed bf16 pairs
    const uint2* __restrict__ Nbit,        // [NS*NN] 64 noise bits
    const int* __restrict__ row_ptr, const int* __restrict__ col_idx,
    const float* __restrict__ eps0p,
    const uint4* __restrict__ Wp,          // packed W0 (NJ=24)
    const float* __restrict__ bias,
    __hip_bfloat16* __restrict__ H) {      // h1 out [NS*NN][256]
    __shared__ unsigned int zt[64 * 96];   // 24 KB z-tile
    const int n0 = blockIdx.x * 32;
    const int tid = threadIdx.x;
    const float c = 1.f + eps0p[0];

    // ---- agg phase: 16 sub-steps, 2 nodes each ----
    for (int jj = 0; jj < 16; ++jj) {
        const int d = n0 + jj * 2 + (tid >> 7);
        if (d < NN) {
            const int nloc = d - n0;
            const int cc = tid & 127;
            const int beg = row_ptr[d], end = row_ptr[d + 1];
            if (cc < 64) {
                const unsigned int* src = Xb + cc;
                unsigned int u = src[(size_t)d * 64];
                float aL = c * bflo(u), aH = c * bfhi(u);
                int e = beg;
                for (; e + 7 < end; e += 8) {    // two x4 brackets: order == two x4 iters
                    unsigned int g0 = src[(size_t)col_idx[e] * 64];
                    unsigned int g1 = src[(size_t)col_idx[e + 1] * 64];
                    unsigned int g2 = src[(size_t)col_idx[e + 2] * 64];
                    unsigned int g3 = src[(size_t)col_idx[e + 3] * 64];
                    unsigned int g4 = src[(size_t)col_idx[e + 4] * 64];
                    unsigned int g5 = src[(size_t)col_idx[e + 5] * 64];
                    unsigned int g6 = src[(size_t)col_idx[e + 6] * 64];
                    unsigned int g7 = src[(size_t)col_idx[e + 7] * 64];
                    aL += (bflo(g0) + bflo(g1)) + (bflo(g2) + bflo(g3));
                    aH += (bfhi(g0) + bfhi(g1)) + (bfhi(g2) + bfhi(g3));
                    aL += (bflo(g4) + bflo(g5)) + (bflo(g6) + bflo(g7));
                    aH += (bfhi(g4) + bfhi(g5)) + (bfhi(g6) + bfhi(g7));
                }
                for (; e + 3 < end; e += 4) {
                    unsigned int g0 = src[(size_t)col_idx[e] * 64];
                    unsigned int g1 = src[(size_t)col_idx[e + 1] * 64];
                    unsigned int g2 = src[(size_t)col_idx[e + 2] * 64];
                    unsigned int g3 = src[(size_t)col_idx[e + 3] * 64];
                    aL += (bflo(g0) + bflo(g1)) + (bflo(g2) + bflo(g3));
                    aH += (bfhi(g0) + bfhi(g1)) + (bfhi(g2) + bfhi(g3));
                }
                for (; e < end; ++e) {
                    unsigned int ue = src[(size_t)col_idx[e] * 64];
                    aL += bflo(ue); aH += bfhi(ue);
                }
                unsigned int r = pack2(aL, aH);
                const int r1 = 32 + nloc;
                zt[(nloc * 96 + cc) ^ ((nloc & 7) << 2)] = r;   // sample 0
                zt[(r1 * 96 + cc) ^ ((r1 & 7) << 2)] = r;       // sample 1 (dedup)
            } else {
                int j = cc - 64;
                int s = j >> 5, col = j & 31;            // dims 2*col, 2*col+1
                const uint2* src = Nbit + (size_t)s * NN;
                const int word = col >> 4;
                const int sh = (2 * col) & 31;
                uint2 uS = src[d];
                unsigned int wS = word ? uS.y : uS.x;
                int c0 = 0, c1 = 0;
                int e = beg;
                for (; e + 3 < end; e += 4) {
                    uint2 u0 = src[col_idx[e]], u1 = src[col_idx[e + 1]];
                    uint2 u2 = src[col_idx[e + 2]], u3 = src[col_idx[e + 3]];
                    unsigned int w0 = word ? u0.y : u0.x, w1 = word ? u1.y : u1.x;
                    unsigned int w2 = word ? u2.y : u2.x, w3 = word ? u3.y : u3.x;
                    c0 += (int)((w0 >> sh) & 1) + (int)((w1 >> sh) & 1) + (int)((w2 >> sh) & 1) + (int)((w3 >> sh) & 1);
                    c1 += (int)((w0 >> (sh + 1)) & 1) + (int)((w1 >> (sh + 1)) & 1) +
                          (int)((w2 >> (sh + 1)) & 1) + (int)((w3 >> (sh + 1)) & 1);
                }
                for (; e < end; ++e) {
                    uint2 ue = src[col_idx[e]];
                    unsigned int we = word ? ue.y : ue.x;
                    c0 += (int)((we >> sh) & 1);
                    c1 += (int)((we >> (sh + 1)) & 1);
                }
                float aL = c * (float)((wS >> sh) & 1) + (float)c0;
                float aH = c * (float)((wS >> (sh + 1)) & 1) + (float)c1;
                const int lr = s * 32 + nloc;
                zt[(lr * 96 + 64 + col) ^ ((lr & 7) << 2)] = pack2(aL, aH);
            }
        }
    }
    __syncthreads();

    // ---- gemm phase: wave w -> rows [w*16, w*16+16), all 256 cols ----
    const int lane = tid & 63, w = tid >> 6;
    const int lo = lane & 15, quad = lane >> 4;
    const int lrow = w * 16 + lo;

    floatx4 acc[16];
#pragma unroll
    for (int t = 0; t < 16; ++t) acc[t] = (floatx4){0.f, 0.f, 0.f, 0.f};

    const uint4* zt4 = (const uint4*)zt;
    for (int ks = 0; ks < 6; ++ks) {        // K=192: 6 k-steps of 32
        bf16x8 a = *(const bf16x8*)&zt4[(lrow * 24 + ks * 4 + quad) ^ (lrow & 7)];
#pragma unroll
        for (int ct = 0; ct < 16; ++ct) {
            bf16x8 b = *(const bf16x8*)&Wp[(size_t)((ct >> 2) * 24 + ks * 4 + quad) * 64 + (ct & 3) * 16 + lo];
            acc[ct] = __builtin_amdgcn_mfma_f32_16x16x32_bf16(a, b, acc[ct], 0, 0, 0);
        }
    }

    const int mbase = w * 16 + quad * 4;
#pragma unroll
    for (int ct = 0; ct < 16; ++ct) {
        const int col = (ct >> 2) * 64 + (ct & 3) * 16 + lo;
        const float bv = bias[col];
#pragma unroll
        for (int r = 0; r < 4; ++r) {
            const int m = mbase + r;                 // 0..63
            const int node = n0 + (m & 31);
            if (node < NN) {
                const int grow = (m >> 5) * NN + node;
                float v = acc[ct][r] + bv;
                H[(size_t)grow * DOUT + col] = __float2bfloat16(v > 0.f ? v : 0.f);
            }
        }
    }
}

#define FUSED0_GRID ((NN + 31) / 32)   // 1563

// ---------------- Layer 1 aggregation (round-0 proven version) ----------------
// 2 nodes/block, per node 2 sample-waves of 64 lanes; uint2 gathers (512B/instr),
// x8 unroll. Measured 116 us @ 76% occupancy.

__global__ __launch_bounds__(256) void agg1_kernel(
    const uint2* __restrict__ h,           // [NS*NN][64] (uint2 = 4 bf16)
    const int* __restrict__ row_ptr, const int* __restrict__ col_idx,
    const float* __restrict__ eps1p,
    uint2* __restrict__ z1) {              // [NS*NN][64]
    const int d = blockIdx.x * 2 + (threadIdx.x >> 7);
    const int s = (threadIdx.x >> 6) & 1;
    const int cc = threadIdx.x & 63;
    const float c = 1.f + eps1p[0];
    const int beg = row_ptr[d], end = row_ptr[d + 1];
    const uint2* src = h + (size_t)s * NN * 64 + cc;
    uint2 u = src[(size_t)d * 64];
    float aL0 = c * bflo(u.x), aH0 = c * bfhi(u.x);
    float aL1 = c * bflo(u.y), aH1 = c * bfhi(u.y);
    int e = beg;
    for (; e + 7 < end; e += 8) {
        uint2 g[8];
#pragma unroll
        for (int q = 0; q < 8; ++q) g[q] = src[(size_t)col_idx[e + q] * 64];
#pragma unroll
        for (int q = 0; q < 8; ++q) {
            aL0 += bflo(g[q].x); aH0 += bfhi(g[q].x);
            aL1 += bflo(g[q].y); aH1 += bfhi(g[q].y);
        }
    }
    for (; e + 3 < end; e += 4) {
        uint2 u0 = src[(size_t)col_idx[e] * 64], u1 = src[(size_t)col_idx[e + 1] * 64];
        uint2 u2 = src[(size_t)col_idx[e + 2] * 64], u3 = src[(size_t)col_idx[e + 3] * 64];
        aL0 += (bflo(u0.x) + bflo(u1.x)) + (bflo(u2.x) + bflo(u3.x));
        aH0 += (bfhi(u0.x) + bfhi(u1.x)) + (bfhi(u2.x) + bfhi(u3.x));
        aL1 += (bflo(u0.y) + bflo(u1.y)) + (bflo(u2.y) + bflo(u3.y));
        aH1 += (bfhi(u0.y) + bfhi(u1.y)) + (bfhi(u2.y) + bfhi(u3.y));
    }
    for (; e < end; ++e) {
        uint2 ue = src[(size_t)col_idx[e] * 64];
        aL0 += bflo(ue.x); aH0 += bfhi(ue.x);
        aL1 += bflo(ue.y); aH1 += bfhi(ue.y);
    }
    uint2 r; r.x = pack2(aL0, aH0); r.y = pack2(aL1, aH1);
    z1[(size_t)(s * NN + d) * 64 + cc] = r;
}

// ---------------- GEMM (layer 1): C = relu(A @ W + b) ----------------
// r6-verified high-TLP single-barrier structure: per-wave 32 rows x 64 cols,
// block 128 rows x 64 cols, whole B panel in LDS, one barrier, NT fp32 stores.

template <bool NT>
__device__ inline void st_out(float* C, size_t idx, float v) {
    if (NT) __builtin_nontemporal_store(v, C + idx); else C[idx] = v;
}
template <bool NT>
__device__ inline void st_out(__hip_bfloat16* C, size_t idx, float v) { C[idx] = __float2bfloat16(v); }

#define GEMM_GRID 3128   // 782 row-groups (128 rows) x 4 col-groups; covers 100096 rows

template <int K, bool NT, typename OUT_T>
__global__ __launch_bounds__(256, 4) void gemm_bias_relu(
    const __hip_bfloat16* __restrict__ A, const uint4* __restrict__ Wp,
    const float* __restrict__ bias, OUT_T* __restrict__ C, int M) {
    constexpr int NJ = K / 8;                 // k-octets per col
    __shared__ uint4 lds[NJ * 64];            // B panel [j][n], 16B elements

    const int p = blockIdx.x;
    const int l = (p & 7) * (GEMM_GRID / 8) + (p >> 3);
    const int cg = l & 3;
    const int rg = l >> 2;
    const int blockRow = rg * 128;

    const int tid = threadIdx.x;
    const uint4* wsrc = Wp + (size_t)cg * (NJ * 64);
#pragma unroll
    for (int i = 0; i < NJ / 4; ++i)
        lds[i * 256 + tid] = wsrc[i * 256 + tid];
    __syncthreads();

    const int lane = tid & 63, wave = tid >> 6;
    const int lo = lane & 15, quad = lane >> 4;
    const int rowBase = blockRow + wave * 32;

    floatx4 acc[2][4];
#pragma unroll
    for (int i = 0; i < 2; ++i)
#pragma unroll
        for (int j = 0; j < 4; ++j) acc[i][j] = (floatx4){0.f, 0.f, 0.f, 0.f};

    unsigned int aoff[2];
#pragma unroll
    for (int rt = 0; rt < 2; ++rt) {
        int rowi = rowBase + rt * 16 + lo;
        if (rowi >= M) rowi = M - 1;
        aoff[rt] = (unsigned int)rowi * (unsigned int)(K * 2);
    }
    const char* Ab = (const char*)A + quad * 16;

#pragma unroll
    for (int ks = 0; ks < K / 32; ++ks) {
        bf16x8 a[2], b[4];
#pragma unroll
        for (int rt = 0; rt < 2; ++rt)
            a[rt] = *(const bf16x8*)(Ab + aoff[rt] + ks * 64);
#pragma unroll
        for (int ct = 0; ct < 4; ++ct)
            b[ct] = *(const bf16x8*)&lds[(ks * 4 + quad) * 64 + ct * 16 + lo];
#pragma unroll
        for (int rt = 0; rt < 2; ++rt)
#pragma unroll
            for (int ct = 0; ct < 4; ++ct)
                acc[rt][ct] = __builtin_amdgcn_mfma_f32_16x16x32_bf16(a[rt], b[ct], acc[rt][ct], 0, 0, 0);
    }

#pragma unroll
    for (int ct = 0; ct < 4; ++ct) {
        const int col = cg * 64 + ct * 16 + lo;
        const float bv = bias[col];
#pragma unroll
        for (int rt = 0; rt < 2; ++rt) {
#pragma unroll
            for (int r = 0; r < 4; ++r) {
                int row = rowBase + rt * 16 + quad * 4 + r;
                if (row < M) {
                    float v = acc[rt][ct][r] + bv;
                    st_out<NT>(C, (size_t)row * DOUT + col, v > 0.f ? v : 0.f);
                }
            }
        }
    }
}

extern "C" void kernel_launch(void* const* d_in, const int* in_sizes, int n_in,
                              void* d_out, int out_size, void* d_ws, size_t ws_size,
                              hipStream_t stream) {
    const float* X = (const float*)d_in[0];
    const float* noise = (const float*)d_in[1];
    const int* esrc = (const int*)d_in[2];
    const int* edst = (const int*)d_in[3];
    const float* W0 = (const float*)d_in[4];
    const float* b0 = (const float*)d_in[5];
    const float* W1 = (const float*)d_in[6];
    const float* b1 = (const float*)d_in[7];
    const float* eps0 = (const float*)d_in[8];
    const float* eps1 = (const float*)d_in[9];
    float* out = (float*)d_out;

    const int M = NS * NN;  // 100000

    // Workspace carve (~56 MB, proven footprint).
    char* w = (char*)d_ws;
    auto carve = [&](size_t bytes) { char* p = w; w += (bytes + 511) & ~(size_t)511; return p; };
    int* cursor = (int*)carve((size_t)NN * 4);
    int* row_ptr = (int*)carve((size_t)(NN + 1) * 4);
    int* col_idx = (int*)carve((size_t)NE * 4);
    int* bsum = (int*)carve((size_t)NB * 4);
    uint2* Nbit = (uint2*)carve((size_t)M * 8);                    // 800 KB, L2-resident
    uint4* Wp0 = (uint4*)carve((size_t)DH0 * DOUT * 2);            // 96 KB packed B, layer 0
    uint4* Wp1 = (uint4*)carve((size_t)DOUT * DOUT * 2);           // 128 KB packed B, layer 1
    unsigned int* z = (unsigned int*)carve((size_t)M * DOUT * 2);  // z1 (64 uint2/row) + Xb tail

    // h1 (bf16, [s][node][256], 51.2 MB) staged at the start of the fp32 out
    // region (102.4 MB); dead before gemm1 overwrites it.
    __hip_bfloat16* h1 = (__hip_bfloat16*)d_out;
    // bf16 X copy (12.8 MB) lives in the TAIL of the z region (dead after
    // fused0's agg phase; agg1's z1 write overwrites it afterwards).
    unsigned short* Xb = (unsigned short*)(z + (size_t)M * 96);

    hipMemsetAsync(cursor, 0, (size_t)NN * 4, stream);
    count_kernel<<<(NE + 255) / 256, 256, 0, stream>>>(edst, cursor);
    scanA_kernel<<<NB, 1024, 0, stream>>>(cursor, bsum);
    scanB_kernel<<<1, 64, 0, stream>>>(bsum);
    scanC_kernel<<<NB, 1024, 0, stream>>>(cursor, bsum, row_ptr);
    fill_kernel<<<(NE + 255) / 256, 256, 0, stream>>>(esrc, edst, cursor, col_idx);
    prep_kernel<<<XB4 + NR_BLOCKS, 256, 0, stream>>>(X, Xb, noise, Nbit,
                                                     out + (size_t)M * DOUT);
    pack_w<DH0><<<DOUT, 64, 0, stream>>>(W0, Wp0);
    pack_w<DOUT><<<DOUT, 64, 0, stream>>>(W1, Wp1);

    fused0_kernel<<<FUSED0_GRID, 256, 0, stream>>>(
        (const unsigned int*)Xb, Nbit, row_ptr, col_idx, eps0, Wp0, b0, h1);
    agg1_kernel<<<NN / 2, 256, 0, stream>>>(
        (const uint2*)h1, row_ptr, col_idx, eps1, (uint2*)z);
    gemm_bias_relu<DOUT, true, float><<<GEMM_GRID, 256, 0, stream>>>(
        (const __hip_bfloat16*)z, Wp1, b1, out, M);
}

// Round 8
// 571.430 us; speedup vs baseline: 1.0922x; 1.0922x over previous
//
#include <hip/hip_runtime.h>
#include <hip/hip_bf16.h>

// Problem constants (from reference)
#define NN 50000      // nodes
#define NE 800000     // edges
#define NS 2          // samples
#define DIN 128
#define DNOISE 64
#define DH0 192       // DIN + DNOISE
#define DOUT 256      // D0 == D1
#define NB 49         // scan blocks = ceil(NN/1024)

typedef __bf16 bf16x8 __attribute__((ext_vector_type(8)));
typedef float floatx4 __attribute__((ext_vector_type(4)));

// ---------------- bf16 helpers (uint = packed bf16 pair) ----------------

__device__ inline float bflo(unsigned int u) { return __uint_as_float(u << 16); }
__device__ inline float bfhi(unsigned int u) { return __uint_as_float(u & 0xffff0000u); }
__device__ inline unsigned short f2bf_bits(float x) {
    __hip_bfloat16 b = __float2bfloat16(x);
    return *reinterpret_cast<unsigned short*>(&b);
}
__device__ inline unsigned int pack2(float lo, float hi) {
    return (unsigned int)f2bf_bits(lo) | ((unsigned int)f2bf_bits(hi) << 16);
}

// ---------------- CSR build ----------------

__global__ void count_kernel(const int* __restrict__ dst, int* __restrict__ cnt) {
    int i = blockIdx.x * blockDim.x + threadIdx.x;
    if (i < NE) atomicAdd(&cnt[dst[i]], 1);
}

// Phase A: per-block reduce of counts -> bsum[49]
__global__ __launch_bounds__(1024) void scanA_kernel(const int* __restrict__ cnt, int* __restrict__ bsum) {
    int i = blockIdx.x * 1024 + threadIdx.x;
    int v = (i < NN) ? cnt[i] : 0;
    for (int off = 32; off > 0; off >>= 1) v += __shfl_down(v, off);
    __shared__ int wsum[16];
    if ((threadIdx.x & 63) == 0) wsum[threadIdx.x >> 6] = v;
    __syncthreads();
    if (threadIdx.x == 0) {
        int s = 0;
        for (int k = 0; k < 16; ++k) s += wsum[k];
        bsum[blockIdx.x] = s;
    }
}

// Phase B: exclusive scan of 49 block sums (single wave, shfl scan)
__global__ __launch_bounds__(64) void scanB_kernel(int* __restrict__ bsum) {
    int lane = threadIdx.x;
    int orig = (lane < NB) ? bsum[lane] : 0;
    int v = orig;
    for (int off = 1; off < 64; off <<= 1) {
        int t = __shfl_up(v, off);
        if (lane >= off) v += t;
    }
    if (lane < NB) bsum[lane] = v - orig;  // exclusive
}

// Phase C: intra-block scan + block offset -> row_ptr, cursor
__global__ __launch_bounds__(1024) void scanC_kernel(int* __restrict__ cnt, const int* __restrict__ bsum,
                                                     int* __restrict__ row_ptr) {
    __shared__ int buf[1024];
    int tid = threadIdx.x;
    int i = blockIdx.x * 1024 + tid;
    int v = (i < NN) ? cnt[i] : 0;
    buf[tid] = v;
    __syncthreads();
    for (int off = 1; off < 1024; off <<= 1) {
        int t = (tid >= off) ? buf[tid - off] : 0;
        __syncthreads();
        buf[tid] += t;
        __syncthreads();
    }
    int excl = buf[tid] - v + bsum[blockIdx.x];
    if (i < NN) { row_ptr[i + 1] = excl + v; cnt[i] = excl; }  // cnt becomes write cursor
    if (i == 0) row_ptr[0] = 0;
}

__global__ void fill_kernel(const int* __restrict__ src, const int* __restrict__ dst,
                            int* __restrict__ cursor, int* __restrict__ col_idx) {
    int i = blockIdx.x * blockDim.x + threadIdx.x;
    if (i < NE) {
        int p = atomicAdd(&cursor[dst[i]], 1);
        col_idx[p] = src[i];
    }
}

// ---------------- input prep: X fp32->bf16 + noise fp32 -> bitpacked uint2 ----------------
// blocks [0, XB4): X convert (float4 granularity). blocks [XB4, XB4+NR): noise rows.
// Noise branch ALSO writes the epsilon passthrough output (fuses old copy_eps).
#define XQ (NN * DIN / 4)          // 1.6M float4 units
#define XB4 ((XQ + 255) / 256)     // 6250
#define NR_BLOCKS ((NS * NN + 255) / 256)  // 391

__global__ void prep_kernel(const float* __restrict__ X, unsigned short* __restrict__ Xb,
                            const float* __restrict__ noise, uint2* __restrict__ Nbit,
                            float* __restrict__ out_eps) {
    int b = blockIdx.x;
    if (b < XB4) {
        int i = b * 256 + threadIdx.x;
        if (i < XQ) {
            float4 v = reinterpret_cast<const float4*>(X)[i];
            ushort4 o;
            o.x = f2bf_bits(v.x); o.y = f2bf_bits(v.y); o.z = f2bf_bits(v.z); o.w = f2bf_bits(v.w);
            reinterpret_cast<ushort4*>(Xb)[i] = o;
        }
    } else {
        int r = (b - XB4) * 256 + threadIdx.x;  // (s*NN + node)
        if (r < NS * NN) {
            const float4* p = reinterpret_cast<const float4*>(noise + (size_t)r * DNOISE);
            float4* oe = reinterpret_cast<float4*>(out_eps + (size_t)r * DNOISE);
            unsigned int lo = 0, hi = 0;
            for (int q = 0; q < 8; ++q) {
                float4 v = p[q];
                oe[q] = v;
                int base = q * 4;
                lo |= (v.x != 0.f ? 1u : 0u) << base;
                lo |= (v.y != 0.f ? 1u : 0u) << (base + 1);
                lo |= (v.z != 0.f ? 1u : 0u) << (base + 2);
                lo |= (v.w != 0.f ? 1u : 0u) << (base + 3);
            }
            for (int q = 8; q < 16; ++q) {
                float4 v = p[q];
                oe[q] = v;
                int base = q * 4 - 32;
                hi |= (v.x != 0.f ? 1u : 0u) << base;
                hi |= (v.y != 0.f ? 1u : 0u) << (base + 1);
                hi |= (v.z != 0.f ? 1u : 0u) << (base + 2);
                hi |= (v.w != 0.f ? 1u : 0u) << (base + 3);
            }
            uint2 o; o.x = lo; o.y = hi;
            Nbit[r] = o;
        }
    }
}

// ---------------- W pack: W[k][n] fp32 -> Wp[cg][j][n'] uint4 (bf16x8 along k) ----------------

template <int K>
__global__ void pack_w(const float* __restrict__ W, uint4* __restrict__ Wp) {
    const int n = blockIdx.x;            // output col 0..255
    const int tj = threadIdx.x;          // k-octet 0..K/8-1
    if (tj < K / 8) {
        unsigned short h[8];
#pragma unroll
        for (int r = 0; r < 8; ++r)
            h[r] = f2bf_bits(W[(size_t)(tj * 8 + r) * DOUT + n]);
        uint4 o;
        o.x = (unsigned)h[0] | ((unsigned)h[1] << 16);
        o.y = (unsigned)h[2] | ((unsigned)h[3] << 16);
        o.z = (unsigned)h[4] | ((unsigned)h[5] << 16);
        o.w = (unsigned)h[6] | ((unsigned)h[7] << 16);
        Wp[(size_t)((n >> 6) * (K / 8) + tj) * 64 + (n & 63)] = o;
    }
}

// ---------------- Layer 0 aggregation (r6-proven) ----------------

__global__ __launch_bounds__(256) void agg0_kernel(
    const unsigned int* __restrict__ Xb,   // [NN][64] packed bf16 pairs
    const uint2* __restrict__ Nbit,        // [NS*NN] 64 noise bits
    const int* __restrict__ row_ptr, const int* __restrict__ col_idx,
    const float* __restrict__ eps0p,
    unsigned int* __restrict__ z0) {       // [NS*NN][96]
    const int d = blockIdx.x * 2 + (threadIdx.x >> 7);
    const int cc = threadIdx.x & 127;
    const float c = 1.f + eps0p[0];
    const int beg = row_ptr[d], end = row_ptr[d + 1];
    if (cc < 64) {
        const unsigned int* src = Xb + cc;
        unsigned int u = src[(size_t)d * 64];
        float aL = c * bflo(u), aH = c * bfhi(u);
        int e = beg;
        for (; e + 3 < end; e += 4) {
            int i0 = col_idx[e], i1 = col_idx[e + 1], i2 = col_idx[e + 2], i3 = col_idx[e + 3];
            unsigned int u0 = src[(size_t)i0 * 64], u1 = src[(size_t)i1 * 64];
            unsigned int u2 = src[(size_t)i2 * 64], u3 = src[(size_t)i3 * 64];
            aL += (bflo(u0) + bflo(u1)) + (bflo(u2) + bflo(u3));
            aH += (bfhi(u0) + bfhi(u1)) + (bfhi(u2) + bfhi(u3));
        }
        for (; e < end; ++e) {
            unsigned int ue = src[(size_t)col_idx[e] * 64];
            aL += bflo(ue); aH += bfhi(ue);
        }
        unsigned int r = pack2(aL, aH);
        z0[(size_t)d * 96 + cc] = r;             // sample 0
        z0[(size_t)(NN + d) * 96 + cc] = r;      // sample 1 (X part sample-independent)
    } else {
        int j = cc - 64;
        int s = j >> 5, col = j & 31;            // dims 2*col, 2*col+1
        const uint2* src = Nbit + (size_t)s * NN;
        const int word = col >> 4;               // 0 -> .x, 1 -> .y
        const int sh = (2 * col) & 31;
        uint2 uS = src[d];
        unsigned int wS = word ? uS.y : uS.x;
        int c0 = 0, c1 = 0;
        int e = beg;
        for (; e + 3 < end; e += 4) {
            uint2 u0 = src[col_idx[e]], u1 = src[col_idx[e + 1]];
            uint2 u2 = src[col_idx[e + 2]], u3 = src[col_idx[e + 3]];
            unsigned int w0 = word ? u0.y : u0.x, w1 = word ? u1.y : u1.x;
            unsigned int w2 = word ? u2.y : u2.x, w3 = word ? u3.y : u3.x;
            c0 += (int)((w0 >> sh) & 1) + (int)((w1 >> sh) & 1) + (int)((w2 >> sh) & 1) + (int)((w3 >> sh) & 1);
            c1 += (int)((w0 >> (sh + 1)) & 1) + (int)((w1 >> (sh + 1)) & 1) +
                  (int)((w2 >> (sh + 1)) & 1) + (int)((w3 >> (sh + 1)) & 1);
        }
        for (; e < end; ++e) {
            uint2 ue = src[col_idx[e]];
            unsigned int we = word ? ue.y : ue.x;
            c0 += (int)((we >> sh) & 1);
            c1 += (int)((we >> (sh + 1)) & 1);
        }
        float aL = c * (float)((wS >> sh) & 1) + (float)c0;
        float aH = c * (float)((wS >> (sh + 1)) & 1) + (float)c1;
        z0[(size_t)(s * NN + d) * 96 + 64 + col] = pack2(aL, aH);
    }
}

// ---------------- GEMM (layer 0): r6-verified high-TLP single-barrier ----------------

template <bool NT>
__device__ inline void st_out(float* C, size_t idx, float v) {
    if (NT) __builtin_nontemporal_store(v, C + idx); else C[idx] = v;
}
template <bool NT>
__device__ inline void st_out(__hip_bfloat16* C, size_t idx, float v) { C[idx] = __float2bfloat16(v); }

#define GEMM_GRID 3128   // 782 row-groups (128 rows) x 4 col-groups; covers 100096 rows

template <int K, bool NT, typename OUT_T>
__global__ __launch_bounds__(256, 4) void gemm_bias_relu(
    const __hip_bfloat16* __restrict__ A, const uint4* __restrict__ Wp,
    const float* __restrict__ bias, OUT_T* __restrict__ C, int M) {
    constexpr int NJ = K / 8;                 // k-octets per col
    __shared__ uint4 lds[NJ * 64];            // B panel [j][n], 16B elements

    const int p = blockIdx.x;
    const int l = (p & 7) * (GEMM_GRID / 8) + (p >> 3);
    const int cg = l & 3;
    const int rg = l >> 2;
    const int blockRow = rg * 128;

    const int tid = threadIdx.x;
    const uint4* wsrc = Wp + (size_t)cg * (NJ * 64);
#pragma unroll
    for (int i = 0; i < NJ / 4; ++i)
        lds[i * 256 + tid] = wsrc[i * 256 + tid];
    __syncthreads();

    const int lane = tid & 63, wave = tid >> 6;
    const int lo = lane & 15, quad = lane >> 4;
    const int rowBase = blockRow + wave * 32;

    floatx4 acc[2][4];
#pragma unroll
    for (int i = 0; i < 2; ++i)
#pragma unroll
        for (int j = 0; j < 4; ++j) acc[i][j] = (floatx4){0.f, 0.f, 0.f, 0.f};

    unsigned int aoff[2];
#pragma unroll
    for (int rt = 0; rt < 2; ++rt) {
        int rowi = rowBase + rt * 16 + lo;
        if (rowi >= M) rowi = M - 1;
        aoff[rt] = (unsigned int)rowi * (unsigned int)(K * 2);
    }
    const char* Ab = (const char*)A + quad * 16;

#pragma unroll
    for (int ks = 0; ks < K / 32; ++ks) {
        bf16x8 a[2], b[4];
#pragma unroll
        for (int rt = 0; rt < 2; ++rt)
            a[rt] = *(const bf16x8*)(Ab + aoff[rt] + ks * 64);
#pragma unroll
        for (int ct = 0; ct < 4; ++ct)
            b[ct] = *(const bf16x8*)&lds[(ks * 4 + quad) * 64 + ct * 16 + lo];
#pragma unroll
        for (int rt = 0; rt < 2; ++rt)
#pragma unroll
            for (int ct = 0; ct < 4; ++ct)
                acc[rt][ct] = __builtin_amdgcn_mfma_f32_16x16x32_bf16(a[rt], b[ct], acc[rt][ct], 0, 0, 0);
    }

#pragma unroll
    for (int ct = 0; ct < 4; ++ct) {
        const int col = cg * 64 + ct * 16 + lo;
        const float bv = bias[col];
#pragma unroll
        for (int rt = 0; rt < 2; ++rt) {
#pragma unroll
            for (int r = 0; r < 4; ++r) {
                int row = rowBase + rt * 16 + quad * 4 + r;
                if (row < M) {
                    float v = acc[rt][ct][r] + bv;
                    st_out<NT>(C, (size_t)row * DOUT + col, v > 0.f ? v : 0.f);
                }
            }
        }
    }
}

// ---------------- FUSED layer 1: agg1 -> 16 KB LDS z1-tile -> GEMM x W1 -> out ----------------
// Block = 256 threads, 16 nodes (32 z1 rows: s*16+nloc). Agg phase = 8 sub-steps
// of the PROVEN agg1 inner loop (2 nodes x 2 sample-waves, uint2 gathers, x8
// unroll, identical summation order), writing uint2 results into a swizzled LDS
// tile instead of global z1 (kills 51.2 MB write + 51.2 MB read of HBM traffic).
// One barrier. GEMM phase: wave w -> rows (w>>1)*16..+16, cols (w&1)*128..+128
// (acc[8] = 32 VGPR); A-frags from swizzled LDS (2-way conflicts only = free);
// B direct from L2-hot packed Wp1 (128 KB, shared by all blocks); bias+relu+NT
// fp32 stores. __launch_bounds__(256,6): 24 waves/CU (agg1's proven TLP) --
// fused0's mistake was capping at 4 blocks/CU. VGPR ~70 fits 6 waves/SIMD.
// h1 lives in WORKSPACE (not d_out), so out-stores cannot race other blocks'
// h1 gathers. Per-output math identical to split agg1+gemm1.

__global__ __launch_bounds__(256, 6) void fused1_kernel(
    const uint2* __restrict__ h,           // h1 in ws: [NS*NN][64] uint2
    const int* __restrict__ row_ptr, const int* __restrict__ col_idx,
    const float* __restrict__ eps1p,
    const uint4* __restrict__ Wp,          // packed W1 (NJ=32)
    const float* __restrict__ bias,
    float* __restrict__ out) {             // [NS*NN][256] fp32
    __shared__ uint2 zt[32 * 64];          // 16 KB z1 tile, 16B-swizzled
    const int n0 = blockIdx.x * 16;
    const int tid = threadIdx.x;
    const float c = 1.f + eps1p[0];

    // ---- agg phase: 8 sub-steps x (2 nodes x 2 sample-waves) ----
    for (int jj = 0; jj < 8; ++jj) {
        const int d = n0 + jj * 2 + (tid >> 7);
        const int nloc = d - n0;                 // 0..15
        const int s = (tid >> 6) & 1;
        const int cc = tid & 63;
        const int beg = row_ptr[d], end = row_ptr[d + 1];
        const uint2* src = h + (size_t)s * NN * 64 + cc;
        uint2 u = src[(size_t)d * 64];
        float aL0 = c * bflo(u.x), aH0 = c * bfhi(u.x);
        float aL1 = c * bflo(u.y), aH1 = c * bfhi(u.y);
        int e = beg;
        for (; e + 7 < end; e += 8) {
            uint2 g[8];
#pragma unroll
            for (int q = 0; q < 8; ++q) g[q] = src[(size_t)col_idx[e + q] * 64];
#pragma unroll
            for (int q = 0; q < 8; ++q) {
                aL0 += bflo(g[q].x); aH0 += bfhi(g[q].x);
                aL1 += bflo(g[q].y); aH1 += bfhi(g[q].y);
            }
        }
        for (; e + 3 < end; e += 4) {
            uint2 u0 = src[(size_t)col_idx[e] * 64], u1 = src[(size_t)col_idx[e + 1] * 64];
            uint2 u2 = src[(size_t)col_idx[e + 2] * 64], u3 = src[(size_t)col_idx[e + 3] * 64];
            aL0 += (bflo(u0.x) + bflo(u1.x)) + (bflo(u2.x) + bflo(u3.x));
            aH0 += (bfhi(u0.x) + bfhi(u1.x)) + (bfhi(u2.x) + bfhi(u3.x));
            aL1 += (bflo(u0.y) + bflo(u1.y)) + (bflo(u2.y) + bflo(u3.y));
            aH1 += (bfhi(u0.y) + bfhi(u1.y)) + (bfhi(u2.y) + bfhi(u3.y));
        }
        for (; e < end; ++e) {
            uint2 ue = src[(size_t)col_idx[e] * 64];
            aL0 += bflo(ue.x); aH0 += bfhi(ue.x);
            aL1 += bflo(ue.y); aH1 += bfhi(ue.y);
        }
        uint2 r; r.x = pack2(aL0, aH0); r.y = pack2(aL1, aH1);
        const int lr = s * 16 + nloc;            // tile row 0..31
        // 16B-granular XOR swizzle: uint4 slot q=cc>>1 -> q^(lr&7)
        zt[lr * 64 + (((cc >> 1) ^ (lr & 7)) << 1) + (cc & 1)] = r;
    }
    __syncthreads();

    // ---- gemm phase: wave w -> rows (w>>1)*16..+16, cols (w&1)*128..+128 ----
    const int lane = tid & 63, w = tid >> 6;
    const int lo = lane & 15, quad = lane >> 4;
    const int rw = w >> 1, ch = w & 1;
    const int lrow = rw * 16 + lo;

    floatx4 acc[8];
#pragma unroll
    for (int t = 0; t < 8; ++t) acc[t] = (floatx4){0.f, 0.f, 0.f, 0.f};

    const uint4* zt4 = (const uint4*)zt;
#pragma unroll
    for (int ks = 0; ks < 8; ++ks) {            // K=256: 8 k-steps of 32
        bf16x8 a = *(const bf16x8*)&zt4[lrow * 32 + ((ks * 4 + quad) ^ (lrow & 7))];
#pragma unroll
        for (int ct = 0; ct < 8; ++ct) {
            // global col n = ch*128 + ct*16 + lo; cg = n>>6 = ch*2 + (ct>>2)
            bf16x8 b = *(const bf16x8*)&Wp[(size_t)((ch * 2 + (ct >> 2)) * 32 + ks * 4 + quad) * 64 + (ct & 3) * 16 + lo];
            acc[ct] = __builtin_amdgcn_mfma_f32_16x16x32_bf16(a, b, acc[ct], 0, 0, 0);
        }
    }

#pragma unroll
    for (int ct = 0; ct < 8; ++ct) {
        const int col = ch * 128 + ct * 16 + lo;
        const float bv = bias[col];
#pragma unroll
        for (int r = 0; r < 4; ++r) {
            const int mrow = rw * 16 + quad * 4 + r;     // 0..31
            const int grow = (mrow >> 4) * NN + n0 + (mrow & 15);
            float v = acc[ct][r] + bv;
            __builtin_nontemporal_store(v > 0.f ? v : 0.f, out + (size_t)grow * DOUT + col);
        }
    }
}

#define FUSED1_GRID (NN / 16)   // 3125, exact

extern "C" void kernel_launch(void* const* d_in, const int* in_sizes, int n_in,
                              void* d_out, int out_size, void* d_ws, size_t ws_size,
                              hipStream_t stream) {
    const float* X = (const float*)d_in[0];
    const float* noise = (const float*)d_in[1];
    const int* esrc = (const int*)d_in[2];
    const int* edst = (const int*)d_in[3];
    const float* W0 = (const float*)d_in[4];
    const float* b0 = (const float*)d_in[5];
    const float* W1 = (const float*)d_in[6];
    const float* b1 = (const float*)d_in[7];
    const float* eps0 = (const float*)d_in[8];
    const float* eps1 = (const float*)d_in[9];
    float* out = (float*)d_out;

    const int M = NS * NN;  // 100000

    // Workspace carve (~56 MB).
    char* w = (char*)d_ws;
    auto carve = [&](size_t bytes) { char* p = w; w += (bytes + 511) & ~(size_t)511; return p; };
    int* cursor = (int*)carve((size_t)NN * 4);
    int* row_ptr = (int*)carve((size_t)(NN + 1) * 4);
    int* col_idx = (int*)carve((size_t)NE * 4);
    int* bsum = (int*)carve((size_t)NB * 4);
    uint2* Nbit = (uint2*)carve((size_t)M * 8);                    // 800 KB, L2-resident
    uint4* Wp0 = (uint4*)carve((size_t)DH0 * DOUT * 2);            // 96 KB packed B, layer 0
    uint4* Wp1 = (uint4*)carve((size_t)DOUT * DOUT * 2);           // 128 KB packed B, layer 1
    char* zreg = carve((size_t)M * DOUT * 2);                      // 51.2 MB multi-use region

    // Buffer plan (no aliasing hazards):
    //   z0 (38.4 MB) -> d_out HEAD [0, 38.4 MB)  (scratch; disjoint from eps tail
    //       at [102.4, 128); dead once fused1 overwrites d_out)
    //   Xb (12.8 MB) -> ws zreg TAIL [38.4, 51.2) (dead after agg0)
    //   h1 (51.2 MB) -> ws zreg [0, 51.2)  (written by gemm0 reading d_out ->
    //       disjoint buffers; overwrites dead Xb; read by fused1 while fused1
    //       writes d_out -> NO RACE)
    unsigned int* z0 = (unsigned int*)d_out;
    unsigned short* Xb = (unsigned short*)(zreg + (size_t)M * 96 * 4);
    __hip_bfloat16* h1 = (__hip_bfloat16*)zreg;

    hipMemsetAsync(cursor, 0, (size_t)NN * 4, stream);
    count_kernel<<<(NE + 255) / 256, 256, 0, stream>>>(edst, cursor);
    scanA_kernel<<<NB, 1024, 0, stream>>>(cursor, bsum);
    scanB_kernel<<<1, 64, 0, stream>>>(bsum);
    scanC_kernel<<<NB, 1024, 0, stream>>>(cursor, bsum, row_ptr);
    fill_kernel<<<(NE + 255) / 256, 256, 0, stream>>>(esrc, edst, cursor, col_idx);
    prep_kernel<<<XB4 + NR_BLOCKS, 256, 0, stream>>>(X, Xb, noise, Nbit,
                                                     out + (size_t)M * DOUT);
    pack_w<DH0><<<DOUT, 64, 0, stream>>>(W0, Wp0);
    pack_w<DOUT><<<DOUT, 64, 0, stream>>>(W1, Wp1);

    agg0_kernel<<<NN / 2, 256, 0, stream>>>(
        (const unsigned int*)Xb, Nbit, row_ptr, col_idx, eps0, z0);
    gemm_bias_relu<DH0, false, __hip_bfloat16><<<GEMM_GRID, 256, 0, stream>>>(
        (const __hip_bfloat16*)z0, Wp0, b0, h1, M);
    fused1_kernel<<<FUSED1_GRID, 256, 0, stream>>>(
        (const uint2*)h1, row_ptr, col_idx, eps1, Wp1, b1, out);
}